// Round 1
// baseline (3584.784 us; speedup 1.0000x reference)
//
#include <hip/hip_runtime.h>
#include <cstddef>

#define NN 10000
#define NE 160000
#define DD 128
#define NG 16

// ---------------------------------------------------------------- sh + node_attr
__global__ void sh_kernel(const float* __restrict__ pos, const int* __restrict__ send,
                          const int* __restrict__ recv, float* __restrict__ ea,
                          float* __restrict__ naS, float* __restrict__ cnt, int E) {
  int e = blockIdx.x * 256 + threadIdx.x;
  if (e >= E) return;
  int s = send[e], r = recv[e];
  float rx = pos[s*3+0] - pos[r*3+0];
  float ry = pos[s*3+1] - pos[r*3+1];
  float rz = pos[s*3+2] - pos[r*3+2];
  float nrm = sqrtf(rx*rx + ry*ry + rz*rz) + 1e-8f;
  float x = rx / nrm, y = ry / nrm, z = rz / nrm;
  float x2 = x*x, y2 = y*y, z2 = z*z;
  float sh[16];
  sh[0] = 1.f;
  sh[1] = 1.7320508f * x;
  sh[2] = 1.7320508f * y;
  sh[3] = 1.7320508f * z;
  sh[4] = 3.8729833f * x * y;
  sh[5] = 3.8729833f * y * z;
  sh[6] = 1.118034f * (3.f * z2 - 1.f);
  sh[7] = 3.8729833f * x * z;
  sh[8] = 1.9364917f * (x2 - y2);
  sh[9] = 2.0916501f * y * (3.f * x2 - y2);
  sh[10] = 10.2469508f * x * y * z;
  sh[11] = 1.6201852f * y * (5.f * z2 - 1.f);
  sh[12] = 1.3228757f * (5.f * z2 - 3.f) * z;
  sh[13] = 1.6201852f * x * (5.f * z2 - 1.f);
  sh[14] = 5.1234754f * z * (x2 - y2);
  sh[15] = 2.0916501f * x * (x2 - 3.f * y2);
  float* ep = ea + (size_t)e * 16;
  *(float4*)(ep+0)  = make_float4(sh[0], sh[1], sh[2], sh[3]);
  *(float4*)(ep+4)  = make_float4(sh[4], sh[5], sh[6], sh[7]);
  *(float4*)(ep+8)  = make_float4(sh[8], sh[9], sh[10], sh[11]);
  *(float4*)(ep+12) = make_float4(sh[12], sh[13], sh[14], sh[15]);
  float* np = naS + (size_t)r * 16;
  #pragma unroll
  for (int k = 0; k < 16; ++k) atomicAdd(np + k, sh[k]);
  atomicAdd(cnt + r, 1.f);
}

__global__ void na_fin(float* __restrict__ na, const float* __restrict__ cnt) {
  int idx = blockIdx.x * 256 + threadIdx.x;   // NN*16 total
  int n = idx >> 4, k = idx & 15;
  float c = fmaxf(cnt[n], 1.f);
  float v = na[idx] / c;
  na[idx] = (k == 0) ? 1.f : v;
}

// ---------------------------------------------------------------- fused tensor-product GEMM
// out[r][j] = act( (sum_k A[r][k]*Wx[k][j] + b[j]) * (sum_{k<16} gate[r][k]*Wa[k][j]) )
// GATHER: A-row = [h[recv[r]] | h[send[r]] | dist[r]]  (KX=257, h stride 128)
template<int KX, bool GATHER, bool SILU, bool BNSTAT>
__launch_bounds__(256, 2)
__global__ void tp_gemm(const float* A,
                        const int* __restrict__ send, const int* __restrict__ recv,
                        const float* __restrict__ dist,
                        const float* __restrict__ gate,
                        const float* __restrict__ Wx, const float* __restrict__ Wa,
                        const float* __restrict__ bias,
                        float* out, int M,
                        double* __restrict__ bn_sum, double* __restrict__ bn_sq)
{
  constexpr int BK = 32;
  constexpr int KMAIN = GATHER ? 256 : KX;
  __shared__ float Asub[BK][64];
  __shared__ float Wsub[BK][128];
  __shared__ float Gt[64][16];
  __shared__ float WaS[16][128];
  __shared__ float distS[GATHER ? 64 : 1];
  __shared__ float bS[BNSTAT ? 512 : 1];
  __shared__ float bQ[BNSTAT ? 512 : 1];

  const int tid = threadIdx.x;
  const int m0 = blockIdx.x * 64;
  const int col0 = (tid & 15) * 8;
  const int e0 = (tid >> 4) * 4;

  // one-time stage: gate tile + Wa
  {
    int e = tid >> 2, q = (tid & 3) * 4;
    int row = m0 + e; if (row >= M) row = M - 1;
    *(float4*)&Gt[e][q] = *(const float4*)(gate + (size_t)row * 16 + q);
    int wr = tid >> 4, wc = (tid & 15) * 8;
    *(float4*)&WaS[wr][wc]     = *(const float4*)(Wa + wr * 128 + wc);
    *(float4*)&WaS[wr][wc + 4] = *(const float4*)(Wa + wr * 128 + wc + 4);
    if constexpr (GATHER) { if (tid < 64) distS[tid] = dist[m0 + tid]; }
  }

  float acc[4][8];
  #pragma unroll
  for (int i = 0; i < 4; ++i)
    #pragma unroll
    for (int j = 0; j < 8; ++j) acc[i][j] = 0.f;

  for (int k0 = 0; k0 < KMAIN; k0 += BK) {
    __syncthreads();
    {
      int el = tid >> 2, koff = (tid & 3) * 8;
      if constexpr (GATHER) {
        int e = m0 + el;
        int node = (k0 < 128) ? recv[e] : send[e];
        const float* src = A + (size_t)node * 128 + (k0 & 127) + koff;
        float4 v0 = *(const float4*)src;
        float4 v1 = *(const float4*)(src + 4);
        Asub[koff+0][el] = v0.x; Asub[koff+1][el] = v0.y;
        Asub[koff+2][el] = v0.z; Asub[koff+3][el] = v0.w;
        Asub[koff+4][el] = v1.x; Asub[koff+5][el] = v1.y;
        Asub[koff+6][el] = v1.z; Asub[koff+7][el] = v1.w;
      } else {
        int row = m0 + el; if (row >= M) row = M - 1;
        #pragma unroll
        for (int h4 = 0; h4 < 2; ++h4) {
          int k = k0 + koff + h4 * 4;
          if (k < KX) {
            float4 v = *(const float4*)(A + (size_t)row * KX + k);
            int kl = k - k0;
            Asub[kl+0][el] = v.x; Asub[kl+1][el] = v.y;
            Asub[kl+2][el] = v.z; Asub[kl+3][el] = v.w;
          }
        }
      }
      int wr = tid >> 3, wc = (tid & 7) * 16;
      int k = k0 + wr;
      if (k < KX) {
        const float* wsrc = Wx + (size_t)k * 128 + wc;
        *(float4*)&Wsub[wr][wc]      = *(const float4*)(wsrc);
        *(float4*)&Wsub[wr][wc + 4]  = *(const float4*)(wsrc + 4);
        *(float4*)&Wsub[wr][wc + 8]  = *(const float4*)(wsrc + 8);
        *(float4*)&Wsub[wr][wc + 12] = *(const float4*)(wsrc + 12);
      }
    }
    __syncthreads();
    const int kc = (KMAIN - k0 >= BK) ? BK : (KMAIN - k0);
    if (kc == BK) {
      #pragma unroll
      for (int kk = 0; kk < BK; ++kk) {
        float4 a4 = *(const float4*)&Asub[kk][e0];
        float4 w0 = *(const float4*)&Wsub[kk][col0];
        float4 w1 = *(const float4*)&Wsub[kk][col0 + 4];
        float av[4] = {a4.x, a4.y, a4.z, a4.w};
        float wv[8] = {w0.x, w0.y, w0.z, w0.w, w1.x, w1.y, w1.z, w1.w};
        #pragma unroll
        for (int i = 0; i < 4; ++i)
          #pragma unroll
          for (int j = 0; j < 8; ++j) acc[i][j] = fmaf(av[i], wv[j], acc[i][j]);
      }
    } else {
      for (int kk = 0; kk < kc; ++kk) {
        float4 a4 = *(const float4*)&Asub[kk][e0];
        float4 w0 = *(const float4*)&Wsub[kk][col0];
        float4 w1 = *(const float4*)&Wsub[kk][col0 + 4];
        float av[4] = {a4.x, a4.y, a4.z, a4.w};
        float wv[8] = {w0.x, w0.y, w0.z, w0.w, w1.x, w1.y, w1.z, w1.w};
        #pragma unroll
        for (int i = 0; i < 4; ++i)
          #pragma unroll
          for (int j = 0; j < 8; ++j) acc[i][j] = fmaf(av[i], wv[j], acc[i][j]);
      }
    }
  }

  // gate path: gac = Gt @ Wa
  float gac[4][8];
  #pragma unroll
  for (int i = 0; i < 4; ++i)
    #pragma unroll
    for (int j = 0; j < 8; ++j) gac[i][j] = 0.f;
  #pragma unroll
  for (int k = 0; k < 16; ++k) {
    float4 w0 = *(const float4*)&WaS[k][col0];
    float4 w1 = *(const float4*)&WaS[k][col0 + 4];
    float wv[8] = {w0.x, w0.y, w0.z, w0.w, w1.x, w1.y, w1.z, w1.w};
    #pragma unroll
    for (int i = 0; i < 4; ++i) {
      float a = Gt[e0 + i][k];
      #pragma unroll
      for (int j = 0; j < 8; ++j) gac[i][j] = fmaf(a, wv[j], gac[i][j]);
    }
  }

  float4 b0 = *(const float4*)(bias + col0);
  float4 b1 = *(const float4*)(bias + col0 + 4);
  float bv[8] = {b0.x, b0.y, b0.z, b0.w, b1.x, b1.y, b1.z, b1.w};
  float w256[8];
  if constexpr (GATHER) {
    float4 u0 = *(const float4*)(Wx + 256 * 128 + col0);
    float4 u1 = *(const float4*)(Wx + 256 * 128 + col0 + 4);
    w256[0]=u0.x; w256[1]=u0.y; w256[2]=u0.z; w256[3]=u0.w;
    w256[4]=u1.x; w256[5]=u1.y; w256[6]=u1.z; w256[7]=u1.w;
  }

  float sloc[8], qloc[8];
  #pragma unroll
  for (int j = 0; j < 8; ++j) { sloc[j] = 0.f; qloc[j] = 0.f; }

  #pragma unroll
  for (int i = 0; i < 4; ++i) {
    int row = m0 + e0 + i;
    float dv = 0.f;
    if constexpr (GATHER) dv = distS[e0 + i];
    float res[8];
    #pragma unroll
    for (int j = 0; j < 8; ++j) {
      float t = acc[i][j];
      if constexpr (GATHER) t = fmaf(dv, w256[j], t);
      t = (t + bv[j]) * gac[i][j];
      if constexpr (SILU) t = t / (1.f + __expf(-t));
      res[j] = t;
      if constexpr (BNSTAT) { sloc[j] += t; qloc[j] = fmaf(t, t, qloc[j]); }
    }
    if (row < M) {
      float* op = out + (size_t)row * 128 + col0;
      *(float4*)op       = make_float4(res[0], res[1], res[2], res[3]);
      *(float4*)(op + 4) = make_float4(res[4], res[5], res[6], res[7]);
    }
  }

  if constexpr (BNSTAT) {
    const int wv_ = tid >> 6, lane = tid & 63;
    #pragma unroll
    for (int j = 0; j < 8; ++j) {
      float s = sloc[j], q = qloc[j];
      s += __shfl_xor(s, 16); q += __shfl_xor(q, 16);
      s += __shfl_xor(s, 32); q += __shfl_xor(q, 32);
      if (lane < 16) { bS[wv_ * 128 + lane * 8 + j] = s; bQ[wv_ * 128 + lane * 8 + j] = q; }
    }
    __syncthreads();
    if (tid < 128) {
      float s = bS[tid] + bS[128 + tid] + bS[256 + tid] + bS[384 + tid];
      float q = bQ[tid] + bQ[128 + tid] + bQ[256 + tid] + bQ[384 + tid];
      atomicAdd(&bn_sum[tid], (double)s);
      atomicAdd(&bn_sq[tid], (double)q);
    }
  }
}

// ---------------------------------------------------------------- BN finalize
__global__ void bn_fin(const double* __restrict__ s, const double* __restrict__ q,
                       const float* __restrict__ g, const float* __restrict__ b,
                       float* __restrict__ sc, float* __restrict__ sh) {
  int c = threadIdx.x;
  double mu = s[c] * (1.0 / NE);
  double var = q[c] * (1.0 / NE) - mu * mu;
  if (var < 0.0) var = 0.0;
  float scale = (float)((double)g[c] / sqrt(var + 1e-5));
  sc[c] = scale;
  sh[c] = b[c] - (float)mu * scale;
}

// ---------------------------------------------------------------- attention + scatter-agg
__global__ void att_agg(const float* __restrict__ m, const float* __restrict__ sc,
                        const float* __restrict__ sh, const float* __restrict__ ea,
                        const float* __restrict__ iWx, const float* __restrict__ iWa,
                        const float* __restrict__ ibp, const int* __restrict__ recv,
                        float* __restrict__ agg, int E) {
  int wave = threadIdx.x >> 6, lane = threadIdx.x & 63;
  int e = blockIdx.x * 4 + wave;
  if (e >= E) return;
  float2 mv  = *(const float2*)(m  + (size_t)e * 128 + lane * 2);
  float2 scv = *(const float2*)(sc + lane * 2);
  float2 shv = *(const float2*)(sh + lane * 2);
  float a0 = fmaf(mv.x, scv.x, shv.x);
  float a1 = fmaf(mv.y, scv.y, shv.y);
  float2 wv = *(const float2*)(iWx + lane * 2);
  float s1 = a0 * wv.x + a1 * wv.y;
  float s2 = (lane < 16) ? ea[(size_t)e * 16 + lane] * iWa[lane] : 0.f;
  #pragma unroll
  for (int o = 32; o > 0; o >>= 1) { s1 += __shfl_xor(s1, o); s2 += __shfl_xor(s2, o); }
  float t = (s1 + ibp[0]) * s2;
  float att = 1.f / (1.f + __expf(-t));
  int r = recv[e];
  atomicAdd(agg + (size_t)r * 128 + lane * 2,     a0 * att);
  atomicAdd(agg + (size_t)r * 128 + lane * 2 + 1, a1 * att);
}

// ---------------------------------------------------------------- softmax + concat build
__global__ void softmax_cat(const float* __restrict__ agg, const float* __restrict__ h,
                            float* __restrict__ ucat, int N) {
  int wave = threadIdx.x >> 6, lane = threadIdx.x & 63;
  int n = blockIdx.x * 4 + wave;
  if (n >= N) return;
  float2 v = *(const float2*)(agg + (size_t)n * 128 + lane * 2);
  float mx = fmaxf(v.x, v.y);
  #pragma unroll
  for (int o = 32; o > 0; o >>= 1) mx = fmaxf(mx, __shfl_xor(mx, o));
  float e0 = __expf(v.x - mx), e1 = __expf(v.y - mx);
  float s = e0 + e1;
  #pragma unroll
  for (int o = 32; o > 0; o >>= 1) s += __shfl_xor(s, o);
  float inv = 1.f / s;
  float2 hv = *(const float2*)(h + (size_t)n * 128 + lane * 2);
  *(float2*)(ucat + (size_t)n * 256 + lane * 2)       = make_float2(e0 * inv * hv.x, e1 * inv * hv.y);
  *(float2*)(ucat + (size_t)n * 256 + 128 + lane * 2) = v;
}

// ---------------------------------------------------------------- graph pooling + head
__global__ void pool_k(const float* __restrict__ h, const int* __restrict__ batch,
                       float* __restrict__ gp, int N) {
  int g = blockIdx.x, j = threadIdx.x;
  int a = 0, b = N;
  while (a < b) { int mid = (a + b) >> 1; if (batch[mid] < g) a = mid + 1; else b = mid; }
  int lo = a;
  a = lo; b = N;
  while (a < b) { int mid = (a + b) >> 1; if (batch[mid] < g + 1) a = mid + 1; else b = mid; }
  int hi = a;
  float s = 0.f;
  for (int n = lo; n < hi; ++n) s += h[(size_t)n * 128 + j];
  gp[g * 128 + j] = s;
}

__global__ void pp1_k(const float* __restrict__ gp, const float* __restrict__ W,
                      const float* __restrict__ b, float* __restrict__ gact) {
  __shared__ float gs[NG * 128];
  for (int i = threadIdx.x; i < NG * 128; i += 256) gs[i] = gp[i];
  __syncthreads();
  for (int r = 0; r < 8; ++r) {
    int o = threadIdx.x + r * 256;
    int g = o >> 7, j = o & 127;
    float s = b[j];
    for (int k = 0; k < 128; ++k) s = fmaf(gs[g * 128 + k], W[k * 128 + j], s);
    gact[o] = s / (1.f + __expf(-s));
  }
}

__global__ void pp2_k(const float* __restrict__ gact, const float* __restrict__ w,
                      const float* __restrict__ b, float* __restrict__ out) {
  int t = threadIdx.x;
  if (t < NG) {
    float s = b[0];
    for (int j = 0; j < 128; ++j) s = fmaf(gact[t * 128 + j], w[j], s);
    out[t] = s;
  }
}

// ---------------------------------------------------------------- host
extern "C" void kernel_launch(void* const* d_in, const int* in_sizes, int n_in,
                              void* d_out, int out_size, void* d_ws, size_t ws_size,
                              hipStream_t stream)
{
  auto F = [&](int i) { return (const float*)d_in[i]; };
  auto I = [&](int i) { return (const int*)d_in[i]; };
  const float* x = F(0);
  const float* pos = F(1);
  const int* batch = I(2);
  const int* iei = I(3);
  const float* iea = F(4);
  const int* eei = I(5);
  const float* eea = F(6);
  const float* embinWx = F(7);  const float* embinWa = F(8);  const float* embinB = F(9);
  const float* emboutWx = F(10); const float* emboutWa = F(11); const float* emboutB = F(12);
  const float* m1Wx = F(13); const float* m1Wa = F(14); const float* m1B = F(15);
  const float* m2Wx = F(16); const float* m2Wa = F(17); const float* m2B = F(18);
  const float* bnG = F(19); const float* bnB = F(20);
  const float* infWx = F(21); const float* infWa = F(22); const float* infB = F(23);
  const float* uWx = F(24); const float* uWa = F(25); const float* uB = F(26);
  const float* ppWx = F(27); const float* ppWa = F(28); const float* ppB = F(29);
  const float* pp1W = F(30); const float* pp1B = F(31);
  const float* pp2W = F(32); const float* pp2B = F(33);
  float* out = (float*)d_out;

  float* ws = (float*)d_ws;
  size_t off = 0;
  auto alloc = [&](size_t n) { float* p = ws + off; off += (n + 63) & ~(size_t)63; return p; };
  float* eaI  = alloc((size_t)NE * 16);
  float* naI  = alloc((size_t)NN * 16);
  float* eaE  = alloc((size_t)NE * 16);
  float* naE  = alloc((size_t)NN * 16);
  float* cntI = alloc(NN);
  float* cntE = alloc(NN);
  float* hA   = alloc((size_t)NN * DD);
  float* hB   = alloc((size_t)NN * DD);
  float* ucat = alloc((size_t)NN * 256);
  float* agg  = alloc((size_t)NN * DD);
  float* bnSC = alloc(DD);
  float* bnSH = alloc(DD);
  float* gp   = alloc(NG * DD);
  float* gact = alloc(NG * DD);
  double* bnSum = (double*)alloc(512);   // 128+128 doubles
  double* bnSq = bnSum + 128;
  float* mbuf = alloc((size_t)NE * DD);

  hipMemsetAsync(naI, 0, (size_t)NN * 16 * 4, stream);
  hipMemsetAsync(naE, 0, (size_t)NN * 16 * 4, stream);
  hipMemsetAsync(cntI, 0, NN * 4, stream);
  hipMemsetAsync(cntE, 0, NN * 4, stream);
  hipMemsetAsync(gp, 0, NG * DD * 4, stream);

  sh_kernel<<<NE / 256, 256, 0, stream>>>(pos, iei, iei + NE, eaI, naI, cntI, NE);
  sh_kernel<<<NE / 256, 256, 0, stream>>>(pos, eei, eei + NE, eaE, naE, cntE, NE);
  na_fin<<<NN * 16 / 256, 256, 0, stream>>>(naI, cntI);
  na_fin<<<NN * 16 / 256, 256, 0, stream>>>(naE, cntE);

  const int gN = (NN + 63) / 64;
  const int gE = NE / 64;

  tp_gemm<16, false, true, false><<<gN, 256, 0, stream>>>(
      x, nullptr, nullptr, nullptr, naI, embinWx, embinWa, embinB, hA, NN, nullptr, nullptr);

  float* hin = hA;
  float* hout = hB;
  for (int l = 0; l < 6; ++l) {
    const bool internal = (l < 3);
    const int* send = internal ? iei : eei;
    const int* recv = send + NE;
    const float* dist = internal ? iea : eea;
    const float* ea = internal ? eaI : eaE;
    const float* na = internal ? naI : naE;

    if (l == 3) {
      tp_gemm<128, false, false, false><<<gN, 256, 0, stream>>>(
          hin, nullptr, nullptr, nullptr, naE, emboutWx, emboutWa, emboutB, hout, NN, nullptr, nullptr);
      float* t = hin; hin = hout; hout = t;
    }

    hipMemsetAsync(agg, 0, (size_t)NN * DD * 4, stream);
    hipMemsetAsync(bnSum, 0, 2048, stream);

    tp_gemm<257, true, true, false><<<gE, 256, 0, stream>>>(
        hin, send, recv, dist, ea,
        m1Wx + (size_t)l * 257 * 128, m1Wa + (size_t)l * 16 * 128, m1B + l * 128,
        mbuf, NE, nullptr, nullptr);
    tp_gemm<128, false, true, true><<<gE, 256, 0, stream>>>(
        mbuf, nullptr, nullptr, nullptr, ea,
        m2Wx + (size_t)l * 128 * 128, m2Wa + (size_t)l * 16 * 128, m2B + l * 128,
        mbuf, NE, bnSum, bnSq);
    bn_fin<<<1, 128, 0, stream>>>(bnSum, bnSq, bnG + l * 128, bnB + l * 128, bnSC, bnSH);
    att_agg<<<NE / 4, 256, 0, stream>>>(mbuf, bnSC, bnSH, ea,
                                        infWx + l * 128, infWa + l * 16, infB + l,
                                        recv, agg, NE);
    softmax_cat<<<(NN + 3) / 4, 256, 0, stream>>>(agg, hin, ucat, NN);
    tp_gemm<256, false, true, false><<<gN, 256, 0, stream>>>(
        ucat, nullptr, nullptr, nullptr, na,
        uWx + (size_t)l * 256 * 128, uWa + (size_t)l * 16 * 128, uB + l * 128,
        hout, NN, nullptr, nullptr);
    float* t = hin; hin = hout; hout = t;
  }

  tp_gemm<128, false, true, false><<<gN, 256, 0, stream>>>(
      hin, nullptr, nullptr, nullptr, naE, ppWx, ppWa, ppB, hout, NN, nullptr, nullptr);
  pool_k<<<NG, 128, 0, stream>>>(hout, batch, gp, NN);
  pp1_k<<<1, 256, 0, stream>>>(gp, pp1W, pp1B, gact);
  pp2_k<<<1, 64, 0, stream>>>(gact, pp2W, pp2B, out);
}